// Round 16
// baseline (1247.228 us; speedup 1.0000x reference)
//
#include <hip/hip_runtime.h>
#include <cstdint>

typedef unsigned short u16;
typedef __attribute__((ext_vector_type(4))) float f32x4;
typedef __attribute__((ext_vector_type(8))) short bf16x8;   // 8 bf16 in 4 VGPRs
typedef __attribute__((ext_vector_type(4))) u16 u16x4;

constexpr int NB = 1024;   // batch
constexpr int NT = 200;    // time
constexpr int ND = 128;    // input dim
constexpr int NU = 128;    // units
constexpr int NG = 512;    // 4*U gates
constexpr int ROWS = 16;   // batch rows per block (MFMA M)
constexpr int NGRP = NB / ROWS;           // 64 groups
constexpr int CHUNK = 4;   // consumer gate granularity (divides NT)
constexpr int ABUF = ROWS * 512;          // 8192 u16 per A buffer
constexpr int LDS_A_ELEMS = 2 * ABUF;     // double-buffered: 32 KiB

__device__ __forceinline__ u16 f2bf(float x) {
    uint32_t u = __builtin_bit_cast(uint32_t, x);
    u = (u + 0x7fffu + ((u >> 16) & 1u)) >> 16;   // RNE
    return (u16)u;
}
__device__ __forceinline__ float bf2f(u16 b) {
    uint32_t u = ((uint32_t)b) << 16;
    return __builtin_bit_cast(float, u);
}
__device__ __forceinline__ float sigm(float x) {
    return __builtin_amdgcn_rcpf(1.f + __expf(-x));
}
// 5-op tanh: mul, exp, add, rcp, fma. Exact at +/-inf (v_exp(inf)=inf ->
// rcp->0 -> 1; v_exp(-inf)=0 -> 1-2 = -1). Replaces the 8-op abs/copysign form.
__device__ __forceinline__ float tanh_cheap(float x) {
    const float e = __expf(2.f * x);
    return 1.f - 2.f * __builtin_amdgcn_rcpf(e + 1.f);
}

// Poll RELAXED (no L2 inv) + periodic acquire (cross-XCD progress guarantee)
// + one final acquire (synchronizes-with edge). r8: acquire every poll = L2
// inv storm. r11: release publish = wbl2 storm. r12: coherent stores +
// relaxed publish, ordering proven by the barrier's per-wave vmcnt drain.
__device__ __forceinline__ void spin_gate(const int* p, int need) {
    int k = 0;
    while (__hip_atomic_load(p, __ATOMIC_RELAXED, __HIP_MEMORY_SCOPE_AGENT) < need) {
        __builtin_amdgcn_s_sleep(16);
        if ((++k & 63) == 0)
            (void)__hip_atomic_load(p, __ATOMIC_ACQUIRE, __HIP_MEMORY_SCOPE_AGENT);
    }
    (void)__hip_atomic_load(p, __ATOMIC_ACQUIRE, __HIP_MEMORY_SCOPE_AGENT);
}

// One LSTM layer scan for 16 batch rows. 3 register weight arrays — exactly 3
// fit the 256-reg/wave budget (512KB CU file / 8 waves); a 4th array or any
// higher occupancy forces global remat (r6/r10/r13: FETCH 7-17GB). No Wk_lo
// (r10: absmax 0.0112 < 0.0188). Double-buffered A -> ONE __syncthreads/step.
// r16: MFMA chains balanced 10/10 (wrl terms split accx/acch), cheap tanh,
// hoisted h-write offsets + u32 row bases, CHUNK=4 (lag 10->6 steps).
template<bool PROD>
__device__ __forceinline__ void run_layer(
    const float* __restrict__ Wk, const float* __restrict__ Wr,
    const float* __restrict__ Bv,
    const float* __restrict__ src,     // PROD: x; CONS: h0 buffer
    float* __restrict__ dst,           // PROD: h0 buffer; CONS: d_out
    u16* A, int* prog_c,
    const int dir, const int base_b,
    const int tid, const int q, const int cl, const int uu,
    const int sr, const int sc)
{
    // ---- resident weight fragments (B-side)
    bf16x8 wkh[4][4], wrh[4][4], wrl[4][4];
    #pragma unroll
    for (int g = 0; g < 4; ++g) {
        const int col = g * NU + uu;
        #pragma unroll
        for (int s = 0; s < 4; ++s) {
            bf16x8 fa, fh, fl;
            #pragma unroll
            for (int j = 0; j < 8; ++j) {
                const int k = s * 32 + q * 8 + j;
                fa[j] = (short)f2bf(Wk[k * NG + col]);
                const float w = Wr[k * NG + col];
                const u16 hi = f2bf(w);
                fh[j] = (short)hi;
                fl[j] = (short)f2bf(w - bf2f(hi));
            }
            wkh[g][s] = fa; wrh[g][s] = fh; wrl[g][s] = fl;
        }
    }
    float bias[4];
    #pragma unroll
    for (int g = 0; g < 4; ++g) bias[g] = Bv[g * NU + uu];

    // hoisted swizzled frag base offsets (u16 index), statically indexed
    uint32_t rb[4];
    #pragma unroll
    for (int s = 0; s < 4; ++s)
        rb[s] = (uint32_t)(cl * 1024 + ((s * 64 + q * 16) ^ ((cl & 15) << 4))) >> 1;
    // hoisted h-write LDS offsets (u16 index, hi plane; lo = +128)
    uint32_t hb4[4];
    // hoisted u32 global row bases (26.2M elems < 2^31: 32-bit safe)
    uint32_t rowb[4];
    #pragma unroll
    for (int j = 0; j < 4; ++j) {
        const int r = q * 4 + j;
        hb4[j] = ((uint32_t)(r * 1024 + ((2 * uu) ^ ((r & 15) << 4))) >> 1) + 256;
        rowb[j] = (uint32_t)(base_b + r) * (NT * NU) + (uint32_t)uu;
    }

    for (int i = tid; i < LDS_A_ELEMS; i += 512) A[i] = 0;   // h planes start 0
    f32x4 cc = {0.f, 0.f, 0.f, 0.f};

    const size_t srow = (size_t)(base_b + sr) * (NT * NU) + sc;
    const uint32_t stg = (uint32_t)(sr * 1024 + ((2 * sc) ^ ((sr & 15) << 4))) >> 1;

    // consumer pre-gate: chunk 0 prefetches through x_{t(CHUNK+1)} -> need +2
    if (!PROD && tid == 0) spin_gate(prog_c, (CHUNK + 2 < NT) ? CHUNK + 2 : NT);
    __syncthreads();   // zeroing ordered before staging (r4 lesson) + gate broadcast

    // prologue: stage x0 into buffer 0; prefetch x1
    {
        const float4 v = *(const float4*)&src[srow + (size_t)(dir ? NT - 1 : 0) * NU];
        const float vv[4] = {v.x, v.y, v.z, v.w};
        u16x4 hi4, lo4;
        #pragma unroll
        for (int e = 0; e < 4; ++e) {
            const u16 h = f2bf(vv[e]);
            hi4[e] = h;
            lo4[e] = f2bf(vv[e] - bf2f(h));
        }
        *(u16x4*)&A[stg]       = hi4;
        *(u16x4*)&A[stg + 128] = lo4;
    }
    float4 cur = *(const float4*)&src[srow + (size_t)(dir ? NT - 2 : 1) * NU];
    __syncthreads();   // x0 staged, visible

    int p = 0;
    for (int cs = 0; cs < NT; cs += CHUNK) {
        // gate chunk cs: prefetches through x_{t(cs+CHUNK+1)} -> need cs+CHUNK+2
        if (!PROD && cs > 0) {
            if (tid == 0) {
                const int need = (cs + CHUNK + 2 < NT) ? cs + CHUNK + 2 : NT;
                spin_gate(prog_c, need);
            }
            __syncthreads();
        }

        for (int step = cs; step < cs + CHUNK; ++step) {
            const int t = dir ? (NT - 1 - step) : step;
            const u16* Ard = A + p * ABUF;
            u16*       Awr = A + (p ^ 1) * ABUF;

            // ---- stage x_{t+1} (prefetched last step) into the NEXT buffer
            if (step + 1 < NT) {
                const float vv[4] = {cur.x, cur.y, cur.z, cur.w};
                u16x4 hi4, lo4;
                #pragma unroll
                for (int e = 0; e < 4; ++e) {
                    const u16 h = f2bf(vv[e]);
                    hi4[e] = h;
                    lo4[e] = f2bf(vv[e] - bf2f(h));
                }
                *(u16x4*)&Awr[stg]       = hi4;   // x_hi: k in [0,128)
                *(u16x4*)&Awr[stg + 128] = lo4;   // x_lo: k in [128,256)
            }
            // ---- prefetch x_{t+2} for next step's staging
            if (step + 2 < NT) {
                const int tf = dir ? (NT - 3 - step) : (step + 2);
                cur = *(const float4*)&src[srow + (size_t)tf * NU];
            }

            f32x4 accx[4], acch[4];   // two balanced 10-deep MFMA chains
            #pragma unroll
            for (int g = 0; g < 4; ++g) {
                accx[g] = (f32x4){bias[g], bias[g], bias[g], bias[g]};
                acch[g] = (f32x4){0.f, 0.f, 0.f, 0.f};
            }

            #pragma unroll
            for (int s = 0; s < 4; ++s) {
                const bf16x8 axh = *(const bf16x8*)&Ard[rb[s]];
                const bf16x8 axl = *(const bf16x8*)&Ard[rb[s] + 128];
                const bf16x8 ahh = *(const bf16x8*)&Ard[rb[s] + 256];
                const bf16x8 ahl = *(const bf16x8*)&Ard[rb[s] + 384];
                #pragma unroll
                for (int g = 0; g < 4; ++g) {
                    accx[g] = __builtin_amdgcn_mfma_f32_16x16x32_bf16(axh, wkh[g][s], accx[g], 0, 0, 0);
                    accx[g] = __builtin_amdgcn_mfma_f32_16x16x32_bf16(axl, wkh[g][s], accx[g], 0, 0, 0);
                    acch[g] = __builtin_amdgcn_mfma_f32_16x16x32_bf16(ahh, wrh[g][s], acch[g], 0, 0, 0);
                    acch[g] = __builtin_amdgcn_mfma_f32_16x16x32_bf16(ahl, wrh[g][s], acch[g], 0, 0, 0);
                    // wrl term: s<2 -> acch, s>=2 -> accx (chains 10/10 not 12/8;
                    // pure reassociation, z = accx+acch unchanged)
                    if (s < 2)
                        acch[g] = __builtin_amdgcn_mfma_f32_16x16x32_bf16(ahh, wrl[g][s], acch[g], 0, 0, 0);
                    else
                        accx[g] = __builtin_amdgcn_mfma_f32_16x16x32_bf16(ahh, wrl[g][s], accx[g], 0, 0, 0);
                }
            }

            // gates + state; C/D: col = lane&15 (unit), row = q*4+j (batch row)
            #pragma unroll
            for (int j = 0; j < 4; ++j) {
                const float gi = sigm(accx[0][j] + acch[0][j]);
                const float gf = sigm(accx[1][j] + acch[1][j]);
                const float gg = tanh_cheap(accx[2][j] + acch[2][j]);
                const float go = sigm(accx[3][j] + acch[3][j]);
                const float cn = gf * cc[j] + gi * gg;
                cc[j] = cn;
                const float h = go * tanh_cheap(cn);
                const u16 hh = f2bf(h);
                const u16 hl = f2bf(h - bf2f(hh));
                Awr[hb4[j]]       = hh;   // h_hi plane of the NEXT buffer
                Awr[hb4[j] + 128] = hl;   // h_lo plane
                const size_t oidx = (size_t)rowb[j] + (size_t)t * NU;
                if (PROD) {
                    // coherent store: at the coherence point once retired
                    __hip_atomic_store(&dst[oidx], h, __ATOMIC_RELAXED,
                                       __HIP_MEMORY_SCOPE_AGENT);
                } else {
                    atomicAdd(&dst[oidx], 0.5f * h);   // fused merge into d_out
                }
            }

            __syncthreads();   // the ONLY per-step barrier: p-reads done,
                               // p^1 writes visible, every wave's older
                               // stores drained (per-wave vmcnt at barrier)
            // publish step+1: h0[0..step] stored AND drained. No waitcnt —
            // the barrier is the proof (r14 lesson: an extra vmcnt(0) here
            // stalls tid0 on its own fresh prefetch).
            if (PROD && tid == 0)
                __hip_atomic_store(prog_c, step + 1, __ATOMIC_RELAXED,
                                   __HIP_MEMORY_SCOPE_AGENT);
            p ^= 1;
        }
    }
}

// grid = (64 groups, 2 dirs, 2 layers) = 256 blocks = 1 per CU, all
// co-resident -> consumer spins cannot deadlock (producers never wait).
__global__ __launch_bounds__(512, 2)
void lstm_scan(const float* __restrict__ x,
               const float* __restrict__ fwk, const float* __restrict__ fwrk,
               const float* __restrict__ fwb,
               const float* __restrict__ bwk, const float* __restrict__ bwrk,
               const float* __restrict__ bwb,
               float* __restrict__ buf_fw, float* __restrict__ buf_bw,
               float* __restrict__ dout, int* __restrict__ prog) {
    __shared__ __align__(16) u16 A[LDS_A_ELEMS];   // 2 x [16][512] bf16, swizzled

    const int tid   = threadIdx.x;
    const int lane  = tid & 63;
    const int wv    = tid >> 6;         // wave 0..7
    const int grp   = blockIdx.x;       // 0..63
    const int dir   = blockIdx.y;       // 0 = fw, 1 = bw
    const int layer = blockIdx.z;       // 0 = producer, 1 = consumer
    const int base_b = grp * ROWS;

    const float* kp = dir ? bwk  : fwk;
    const float* rp = dir ? bwrk : fwrk;
    const float* bp = dir ? bwb  : fwb;
    float* buf = dir ? buf_bw : buf_fw;
    int* prog_c = prog + dir * NGRP + grp;

    const int q  = lane >> 4;           // k-group 0..3
    const int cl = lane & 15;           // A-row / B-col within tile
    const int uu = (wv << 4) + cl;      // unit 0..127 owned by this lane

    const int sr = tid >> 5;            // staging row 0..15
    const int sc = (tid & 31) << 2;     // staging col 0..124

    if (layer == 0) {
        // layer 0: x -> buf (h0), publishing progress per step
        run_layer<true>(kp, rp, bp, x, buf, A, prog_c,
                        dir, base_b, tid, q, cl, uu, sr, sc);
    } else {
        // layer 1: buf (h0) -> 0.5*h1 accumulated into d_out, gated on
        // producer progress. buf is read-only here (no aliasing).
        run_layer<false>(kp + ND * NG, rp + NU * NG, bp + NG,
                         buf, dout, A, prog_c,
                         dir, base_b, tid, q, cl, uu, sr, sc);
    }
}

extern "C" void kernel_launch(void* const* d_in, const int* in_sizes, int n_in,
                              void* d_out, int out_size, void* d_ws, size_t ws_size,
                              hipStream_t stream) {
    const float* x    = (const float*)d_in[0];
    const float* fwk  = (const float*)d_in[1];
    const float* fwrk = (const float*)d_in[2];
    const float* fwb  = (const float*)d_in[3];
    const float* bwk  = (const float*)d_in[4];
    const float* bwrk = (const float*)d_in[5];
    const float* bwb  = (const float*)d_in[6];
    float* out = (float*)d_out;

    const size_t seq = (size_t)NB * NT * NU;     // 26,214,400 elements
    float* buf_fw = (float*)d_ws;                // fw h0 sequence
    float* buf_bw = buf_fw + seq;                // bw h0 sequence
    int*   prog   = (int*)(buf_bw + seq);        // per-chain progress counters

    // deterministic replay: zero counters and the atomicAdd target each launch
    hipMemsetAsync(prog, 0, 2 * NGRP * sizeof(int), stream);
    hipMemsetAsync(out, 0, (size_t)out_size * sizeof(float), stream);

    lstm_scan<<<dim3(NGRP, 2, 2), 512, 0, stream>>>(
        x, fwk, fwrk, fwb, bwk, bwrk, bwb, buf_fw, buf_bw, out, prog);
}

// Round 17
// 981.152 us; speedup vs baseline: 1.2712x; 1.2712x over previous
//
#include <hip/hip_runtime.h>
#include <cstdint>

typedef unsigned short u16;
typedef __attribute__((ext_vector_type(4))) float f32x4;
typedef __attribute__((ext_vector_type(8))) short bf16x8;   // 8 bf16 in 4 VGPRs
typedef __attribute__((ext_vector_type(4))) u16 u16x4;

constexpr int NB = 1024;   // batch
constexpr int NT = 200;    // time
constexpr int ND = 128;    // input dim
constexpr int NU = 128;    // units
constexpr int NG = 512;    // 4*U gates
constexpr int ROWS = 16;   // batch rows per block (MFMA M)
constexpr int NGRP = NB / ROWS;           // 64 groups
constexpr int CHUNK = 8;   // consumer gate granularity (r16: CHUNK=4 doubled
                           // the acquire/buffer_inv count -> +48MB refetch,
                           // -27% perf. Keep gates >= 8 steps apart.)
constexpr int ABUF = ROWS * 512;          // 8192 u16 per A buffer
constexpr int LDS_A_ELEMS = 2 * ABUF;     // double-buffered: 32 KiB

__device__ __forceinline__ u16 f2bf(float x) {
    uint32_t u = __builtin_bit_cast(uint32_t, x);
    u = (u + 0x7fffu + ((u >> 16) & 1u)) >> 16;   // RNE
    return (u16)u;
}
__device__ __forceinline__ float bf2f(u16 b) {
    uint32_t u = ((uint32_t)b) << 16;
    return __builtin_bit_cast(float, u);
}
__device__ __forceinline__ float sigm(float x) {
    return __builtin_amdgcn_rcpf(1.f + __expf(-x));
}
// 5-op tanh (r16-validated bit-identical absmax): exact at +/-inf.
__device__ __forceinline__ float tanh_cheap(float x) {
    const float e = __expf(2.f * x);
    return 1.f - 2.f * __builtin_amdgcn_rcpf(e + 1.f);
}

// Poll RELAXED (no L2 inv) + periodic acquire (cross-XCD progress guarantee)
// + one final acquire (synchronizes-with edge). r8: acquire every poll = L2
// inv storm. r11: release publish = wbl2 storm. r12: coherent stores +
// relaxed publish, ordering proven by the barrier's per-wave vmcnt drain.
__device__ __forceinline__ void spin_gate(const int* p, int need) {
    int k = 0;
    while (__hip_atomic_load(p, __ATOMIC_RELAXED, __HIP_MEMORY_SCOPE_AGENT) < need) {
        __builtin_amdgcn_s_sleep(16);
        if ((++k & 63) == 0)
            (void)__hip_atomic_load(p, __ATOMIC_ACQUIRE, __HIP_MEMORY_SCOPE_AGENT);
    }
    (void)__hip_atomic_load(p, __ATOMIC_ACQUIRE, __HIP_MEMORY_SCOPE_AGENT);
}

// One LSTM layer scan for 16 batch rows. 3 register weight arrays — exactly 3
// fit the 256-reg/wave budget (512KB CU file / 8 waves); a 4th array or any
// higher occupancy forces global remat (r6/r10/r13: FETCH 7-17GB). No Wk_lo
// (r10: absmax 0.0112 < 0.0188). Double-buffered A -> ONE __syncthreads/step.
// PROD stores h0 as relaxed agent atomics (write-through; no wbl2) and
// publishes progress relaxed after the barrier. CONS accumulates 0.5*h1
// straight into d_out via atomicAdd (2 commutative addends -> deterministic).
template<bool PROD>
__device__ __forceinline__ void run_layer(
    const float* __restrict__ Wk, const float* __restrict__ Wr,
    const float* __restrict__ Bv,
    const float* __restrict__ src,     // PROD: x; CONS: h0 buffer
    float* __restrict__ dst,           // PROD: h0 buffer; CONS: d_out
    u16* A, int* prog_c,
    const int dir, const int base_b,
    const int tid, const int q, const int cl, const int uu,
    const int sr, const int sc)
{
    // ---- resident weight fragments (B-side)
    bf16x8 wkh[4][4], wrh[4][4], wrl[4][4];
    #pragma unroll
    for (int g = 0; g < 4; ++g) {
        const int col = g * NU + uu;
        #pragma unroll
        for (int s = 0; s < 4; ++s) {
            bf16x8 fa, fh, fl;
            #pragma unroll
            for (int j = 0; j < 8; ++j) {
                const int k = s * 32 + q * 8 + j;
                fa[j] = (short)f2bf(Wk[k * NG + col]);
                const float w = Wr[k * NG + col];
                const u16 hi = f2bf(w);
                fh[j] = (short)hi;
                fl[j] = (short)f2bf(w - bf2f(hi));
            }
            wkh[g][s] = fa; wrh[g][s] = fh; wrl[g][s] = fl;
        }
    }
    float bias[4];
    #pragma unroll
    for (int g = 0; g < 4; ++g) bias[g] = Bv[g * NU + uu];

    // hoisted swizzled frag base offsets (u16 index), statically indexed
    uint32_t rb[4];
    #pragma unroll
    for (int s = 0; s < 4; ++s)
        rb[s] = (uint32_t)(cl * 1024 + ((s * 64 + q * 16) ^ ((cl & 15) << 4))) >> 1;
    // hoisted h-write LDS offsets (u16 index, hi plane; lo = +128)
    uint32_t hb4[4];
    // hoisted u32 global row bases (26.2M elems < 2^31: 32-bit safe)
    uint32_t rowb[4];
    #pragma unroll
    for (int j = 0; j < 4; ++j) {
        const int r = q * 4 + j;
        hb4[j] = ((uint32_t)(r * 1024 + ((2 * uu) ^ ((r & 15) << 4))) >> 1) + 256;
        rowb[j] = (uint32_t)(base_b + r) * (NT * NU) + (uint32_t)uu;
    }

    for (int i = tid; i < LDS_A_ELEMS; i += 512) A[i] = 0;   // h planes start 0
    f32x4 cc = {0.f, 0.f, 0.f, 0.f};

    const size_t srow = (size_t)(base_b + sr) * (NT * NU) + sc;
    const uint32_t stg = (uint32_t)(sr * 1024 + ((2 * sc) ^ ((sr & 15) << 4))) >> 1;

    // consumer pre-gate: chunk 0 prefetches through x_{t(9)} -> need 10
    if (!PROD && tid == 0) spin_gate(prog_c, (CHUNK + 2 < NT) ? CHUNK + 2 : NT);
    __syncthreads();   // zeroing ordered before staging (r4 lesson) + gate broadcast

    // prologue: stage x0 into buffer 0; prefetch x1
    {
        const float4 v = *(const float4*)&src[srow + (size_t)(dir ? NT - 1 : 0) * NU];
        const float vv[4] = {v.x, v.y, v.z, v.w};
        u16x4 hi4, lo4;
        #pragma unroll
        for (int e = 0; e < 4; ++e) {
            const u16 h = f2bf(vv[e]);
            hi4[e] = h;
            lo4[e] = f2bf(vv[e] - bf2f(h));
        }
        *(u16x4*)&A[stg]       = hi4;
        *(u16x4*)&A[stg + 128] = lo4;
    }
    float4 cur = *(const float4*)&src[srow + (size_t)(dir ? NT - 2 : 1) * NU];
    __syncthreads();   // x0 staged, visible

    int p = 0;
    for (int cs = 0; cs < NT; cs += CHUNK) {
        // gate chunk cs: prefetches through x_{t(cs+9)} -> need cs+10
        if (!PROD && cs > 0) {
            if (tid == 0) {
                const int need = (cs + CHUNK + 2 < NT) ? cs + CHUNK + 2 : NT;
                spin_gate(prog_c, need);
            }
            __syncthreads();
        }

        for (int step = cs; step < cs + CHUNK; ++step) {
            const int t = dir ? (NT - 1 - step) : step;
            const u16* Ard = A + p * ABUF;
            u16*       Awr = A + (p ^ 1) * ABUF;

            // ---- stage x_{t+1} (prefetched last step) into the NEXT buffer
            if (step + 1 < NT) {
                const float vv[4] = {cur.x, cur.y, cur.z, cur.w};
                u16x4 hi4, lo4;
                #pragma unroll
                for (int e = 0; e < 4; ++e) {
                    const u16 h = f2bf(vv[e]);
                    hi4[e] = h;
                    lo4[e] = f2bf(vv[e] - bf2f(h));
                }
                *(u16x4*)&Awr[stg]       = hi4;   // x_hi: k in [0,128)
                *(u16x4*)&Awr[stg + 128] = lo4;   // x_lo: k in [128,256)
            }
            // ---- prefetch x_{t+2} for next step's staging
            if (step + 2 < NT) {
                const int tf = dir ? (NT - 3 - step) : (step + 2);
                cur = *(const float4*)&src[srow + (size_t)tf * NU];
            }

            f32x4 accx[4], acch[4];   // x-side (carries bias) and h-side chains
            #pragma unroll
            for (int g = 0; g < 4; ++g) {
                accx[g] = (f32x4){bias[g], bias[g], bias[g], bias[g]};
                acch[g] = (f32x4){0.f, 0.f, 0.f, 0.f};
            }

            #pragma unroll
            for (int s = 0; s < 4; ++s) {
                const bf16x8 axh = *(const bf16x8*)&Ard[rb[s]];
                const bf16x8 axl = *(const bf16x8*)&Ard[rb[s] + 128];
                const bf16x8 ahh = *(const bf16x8*)&Ard[rb[s] + 256];
                const bf16x8 ahl = *(const bf16x8*)&Ard[rb[s] + 384];
                #pragma unroll
                for (int g = 0; g < 4; ++g) {
                    accx[g] = __builtin_amdgcn_mfma_f32_16x16x32_bf16(axh, wkh[g][s], accx[g], 0, 0, 0);
                    accx[g] = __builtin_amdgcn_mfma_f32_16x16x32_bf16(axl, wkh[g][s], accx[g], 0, 0, 0);
                    acch[g] = __builtin_amdgcn_mfma_f32_16x16x32_bf16(ahh, wrh[g][s], acch[g], 0, 0, 0);
                    acch[g] = __builtin_amdgcn_mfma_f32_16x16x32_bf16(ahl, wrh[g][s], acch[g], 0, 0, 0);
                    acch[g] = __builtin_amdgcn_mfma_f32_16x16x32_bf16(ahh, wrl[g][s], acch[g], 0, 0, 0);
                }
            }

            // gates + state; C/D: col = lane&15 (unit), row = q*4+j (batch row)
            #pragma unroll
            for (int j = 0; j < 4; ++j) {
                const float gi = sigm(accx[0][j] + acch[0][j]);
                const float gf = sigm(accx[1][j] + acch[1][j]);
                const float gg = tanh_cheap(accx[2][j] + acch[2][j]);
                const float go = sigm(accx[3][j] + acch[3][j]);
                const float cn = gf * cc[j] + gi * gg;
                cc[j] = cn;
                const float h = go * tanh_cheap(cn);
                const u16 hh = f2bf(h);
                const u16 hl = f2bf(h - bf2f(hh));
                Awr[hb4[j]]       = hh;   // h_hi plane of the NEXT buffer
                Awr[hb4[j] + 128] = hl;   // h_lo plane
                const size_t oidx = (size_t)rowb[j] + (size_t)t * NU;
                if (PROD) {
                    // coherent store: at the coherence point once retired
                    __hip_atomic_store(&dst[oidx], h, __ATOMIC_RELAXED,
                                       __HIP_MEMORY_SCOPE_AGENT);
                } else {
                    atomicAdd(&dst[oidx], 0.5f * h);   // fused merge into d_out
                }
            }

            __syncthreads();   // the ONLY per-step barrier: p-reads done,
                               // p^1 writes visible, every wave's older
                               // stores drained (per-wave vmcnt at barrier)
            // publish step+1: h0[0..step] stored AND drained. No waitcnt —
            // the barrier is the proof (r14 lesson: an extra vmcnt(0) here
            // stalls tid0 on its own fresh prefetch).
            if (PROD && tid == 0)
                __hip_atomic_store(prog_c, step + 1, __ATOMIC_RELAXED,
                                   __HIP_MEMORY_SCOPE_AGENT);
            p ^= 1;
        }
    }
}

// grid = (64 groups, 2 dirs, 2 layers) = 256 blocks = 1 per CU, all
// co-resident -> consumer spins cannot deadlock (producers never wait).
__global__ __launch_bounds__(512, 2)
void lstm_scan(const float* __restrict__ x,
               const float* __restrict__ fwk, const float* __restrict__ fwrk,
               const float* __restrict__ fwb,
               const float* __restrict__ bwk, const float* __restrict__ bwrk,
               const float* __restrict__ bwb,
               float* __restrict__ buf_fw, float* __restrict__ buf_bw,
               float* __restrict__ dout, int* __restrict__ prog) {
    __shared__ __align__(16) u16 A[LDS_A_ELEMS];   // 2 x [16][512] bf16, swizzled

    const int tid   = threadIdx.x;
    const int lane  = tid & 63;
    const int wv    = tid >> 6;         // wave 0..7
    const int grp   = blockIdx.x;       // 0..63
    const int dir   = blockIdx.y;       // 0 = fw, 1 = bw
    const int layer = blockIdx.z;       // 0 = producer, 1 = consumer
    const int base_b = grp * ROWS;

    const float* kp = dir ? bwk  : fwk;
    const float* rp = dir ? bwrk : fwrk;
    const float* bp = dir ? bwb  : fwb;
    float* buf = dir ? buf_bw : buf_fw;
    int* prog_c = prog + dir * NGRP + grp;

    const int q  = lane >> 4;           // k-group 0..3
    const int cl = lane & 15;           // A-row / B-col within tile
    const int uu = (wv << 4) + cl;      // unit 0..127 owned by this lane

    const int sr = tid >> 5;            // staging row 0..15
    const int sc = (tid & 31) << 2;     // staging col 0..124

    if (layer == 0) {
        // layer 0: x -> buf (h0), publishing progress per step
        run_layer<true>(kp, rp, bp, x, buf, A, prog_c,
                        dir, base_b, tid, q, cl, uu, sr, sc);
    } else {
        // layer 1: buf (h0) -> 0.5*h1 accumulated into d_out, gated on
        // producer progress. buf is read-only here (no aliasing).
        run_layer<false>(kp + ND * NG, rp + NU * NG, bp + NG,
                         buf, dout, A, prog_c,
                         dir, base_b, tid, q, cl, uu, sr, sc);
    }
}

extern "C" void kernel_launch(void* const* d_in, const int* in_sizes, int n_in,
                              void* d_out, int out_size, void* d_ws, size_t ws_size,
                              hipStream_t stream) {
    const float* x    = (const float*)d_in[0];
    const float* fwk  = (const float*)d_in[1];
    const float* fwrk = (const float*)d_in[2];
    const float* fwb  = (const float*)d_in[3];
    const float* bwk  = (const float*)d_in[4];
    const float* bwrk = (const float*)d_in[5];
    const float* bwb  = (const float*)d_in[6];
    float* out = (float*)d_out;

    const size_t seq = (size_t)NB * NT * NU;     // 26,214,400 elements
    float* buf_fw = (float*)d_ws;                // fw h0 sequence
    float* buf_bw = buf_fw + seq;                // bw h0 sequence
    int*   prog   = (int*)(buf_bw + seq);        // per-chain progress counters

    // deterministic replay: zero counters and the atomicAdd target each launch
    hipMemsetAsync(prog, 0, 2 * NGRP * sizeof(int), stream);
    hipMemsetAsync(out, 0, (size_t)out_size * sizeof(float), stream);

    lstm_scan<<<dim3(NGRP, 2, 2), 512, 0, stream>>>(
        x, fwk, fwrk, fwb, bwk, bwrk, bwb, buf_fw, buf_bw, out, prog);
}